// Round 15
// baseline (196.413 us; speedup 1.0000x reference)
//
#include <hip/hip_runtime.h>
#include <stdint.h>

#define H_B  4
#define H_SQ 1024
#define H_SK 2048
#define H_D  1024
#define H_NH 16
#define H_DH 64

typedef __bf16 bf16x8 __attribute__((ext_vector_type(8)));
typedef float  f32x4  __attribute__((ext_vector_type(4)));

__device__ __forceinline__ uint16_t f2bf(float f) {
    union { float f; uint32_t u; } v; v.f = f;
    uint32_t r = v.u + 0x7fffu + ((v.u >> 16) & 1u);
    return (uint16_t)(r >> 16);
}

__device__ __forceinline__ void gload_lds16(const void* g, void* l) {
    __builtin_amdgcn_global_load_lds(
        (const __attribute__((address_space(1))) uint32_t*)g,
        (__attribute__((address_space(3))) uint32_t*)l, 16, 0, 0);
}

#define MFMA_BF16(a, b, c) __builtin_amdgcn_mfma_f32_16x16x32_bf16((a), (b), (c), 0, 0, 0)
#define EXP2(x) __builtin_amdgcn_exp2f(x)

// DPP crosslane (VALU pipe — not DS): xor within 16-lane row groups
template <int CTRL>
__device__ __forceinline__ float dpp_xor(float v) {
    return __builtin_bit_cast(float,
        __builtin_amdgcn_update_dpp(__builtin_bit_cast(int, v),
                                    __builtin_bit_cast(int, v),
                                    CTRL, 0xF, 0xF, false));
}
#define DPP_XOR1 0xB1   // quad_perm(1,0,3,2)
#define DPP_XOR2 0x4E   // quad_perm(2,3,0,1)
#define DPP_XOR4 0x141  // row_half_mirror
#define DPP_XOR8 0x140  // row_mirror

__device__ __forceinline__ float dpp_max16(float v) {
    v = fmaxf(v, dpp_xor<DPP_XOR1>(v));
    v = fmaxf(v, dpp_xor<DPP_XOR2>(v));
    v = fmaxf(v, dpp_xor<DPP_XOR4>(v));
    v = fmaxf(v, dpp_xor<DPP_XOR8>(v));
    return v;
}
__device__ __forceinline__ float dpp_sum16(float v) {
    v += dpp_xor<DPP_XOR1>(v);
    v += dpp_xor<DPP_XOR2>(v);
    v += dpp_xor<DPP_XOR4>(v);
    v += dpp_xor<DPP_XOR8>(v);
    return v;
}

// ---------------- prep: 3 weight transposes only (x/ctx cvt fused into GEMM) ----
__global__ __launch_bounds__(256) void prep_kernel(
    const float* __restrict__ Wq, uint16_t* __restrict__ WqT,
    const float* __restrict__ Wkv, uint16_t* __restrict__ WkvT,
    const float* __restrict__ Wp, uint16_t* __restrict__ WpT)
{
    __shared__ float tile[32][33];
    int bid = blockIdx.x;
    int t = threadIdx.x;
    int bx = bid & 127, k0 = (bid >> 7) * 32;
    const float* W; uint16_t* WT; int N, n0;
    if (bx < 32)      { W = Wq;  WT = WqT;  N = 1024; n0 = bx * 32; }
    else if (bx < 96) { W = Wkv; WT = WkvT; N = 2048; n0 = (bx - 32) * 32; }
    else              { W = Wp;  WT = WpT;  N = 1024; n0 = (bx - 96) * 32; }
    int tx = t & 31, ty = t >> 5;            // (32,8) reshaped
    #pragma unroll
    for (int i = ty; i < 32; i += 8)
        tile[i][tx] = W[(size_t)(k0 + i) * N + n0 + tx];
    __syncthreads();
    #pragma unroll
    for (int i = ty; i < 32; i += 8)
        WT[(size_t)(n0 + i) * 1024 + k0 + tx] = f2bf(tile[tx][i]);
}

// ---------------- GEMM body: C[M][N] = A[M][K] @ BT[N][K]^T + bias --------------
// 2-phase double-buffered LDS (bf16 in LDS always). AF32: A is f32 in global,
// reg-staged (global f32 -> reg -> cvt_pk -> ds_write_b128); loads issue at
// tile top, cvt+write after the MFMA block (latency hidden under compute).
// LDS footprint identical to the bf16 path -> occupancy unchanged.
// MODE 0: bf16 C. MODE 1: f32 C.
// MODE 2 (kv projection, BM=128): cols < H_D -> kb[row][col] (stride H_D);
//   cols >= H_D -> vT[(b*16+hh)*64+dd][sk] transposed, packed uint2 (fused vtrans).
template <int MODE, int BM, bool AF32>
__device__ __forceinline__ void gemm_body(
    const void* __restrict__ A, const uint16_t* __restrict__ BT,
    const float* __restrict__ bias, void* __restrict__ Cv,
    uint16_t* __restrict__ vTb, int M, int N, int K,
    int wg, int nwg, char* smem)
{
    constexpr int MI = BM / 32;              // acc rows of 16x16 frags per wave
    uint16_t (*As)[BM * 32] = (uint16_t (*)[BM * 32])smem;
    uint16_t (*Bs)[128 * 32] = (uint16_t (*)[128 * 32])(smem + 2 * BM * 32 * 2);

    int nbn = N >> 7;
    int cpx = nwg >> 3;                         // nwg divisible by 8 for all our shapes
    wg = (wg & 7) * cpx + (wg >> 3);            // XCD-aware swizzle (bijective)
    int bm = wg / nbn, bn = wg % nbn;

    int t = threadIdx.x;
    int w = t >> 6, l = t & 63;
    int lr = l & 15, lg = l >> 4;
    int wr = (w >> 1) * (BM / 2), wc = (w & 1) * 64;

    const uint16_t* Ab16 = nullptr;
    const float*    Abf  = nullptr;
    if constexpr (AF32) Abf  = (const float*)A + (size_t)bm * BM * K;
    else                Ab16 = (const uint16_t*)A + (size_t)bm * BM * K;
    const uint16_t* Bb = BT + (size_t)bn * 128 * K;

    // B staging chunk geometry (16B chunks): chunk c -> row c>>2, piece c&3
    int ca = w * 64 + l;
    int rowa = ca >> 2, kpa = (ca & 3) * 8;
    int cb = 256 + ca;
    int rowb = cb >> 2, kpb = (cb & 3) * 8;
    int offa = ca * 16;          // linear LDS byte offsets (dest = base + lane*16)
    int offb = cb * 16;

    // A chunk geometry (bf16 16B chunks in LDS): BM*32 elems -> BM*4 chunks
    int rA0 = ca >> 2, kA0 = (ca & 3) * 8;     // chunk t
    int rA1 = cb >> 2, kA1 = (cb & 3) * 8;     // chunk t+256 (BM==128 only)

    f32x4 acc[MI][4];
    #pragma unroll
    for (int i = 0; i < MI; ++i)
        #pragma unroll
        for (int j = 0; j < 4; ++j) acc[i][j] = {0.f, 0.f, 0.f, 0.f};

    // prologue: stage k0 = 0 into buffer 0
    if constexpr (AF32) {
        float4 u0 = *(const float4*)(Abf + (size_t)rA0 * K + kA0);
        float4 v0 = *(const float4*)(Abf + (size_t)rA0 * K + kA0 + 4);
        bf16x8 o0;
        o0[0] = (__bf16)u0.x; o0[1] = (__bf16)u0.y; o0[2] = (__bf16)u0.z; o0[3] = (__bf16)u0.w;
        o0[4] = (__bf16)v0.x; o0[5] = (__bf16)v0.y; o0[6] = (__bf16)v0.z; o0[7] = (__bf16)v0.w;
        *(bf16x8*)((char*)As[0] + ca * 16) = o0;
        if constexpr (BM == 128) {
            float4 u1 = *(const float4*)(Abf + (size_t)rA1 * K + kA1);
            float4 v1 = *(const float4*)(Abf + (size_t)rA1 * K + kA1 + 4);
            bf16x8 o1;
            o1[0] = (__bf16)u1.x; o1[1] = (__bf16)u1.y; o1[2] = (__bf16)u1.z; o1[3] = (__bf16)u1.w;
            o1[4] = (__bf16)v1.x; o1[5] = (__bf16)v1.y; o1[6] = (__bf16)v1.z; o1[7] = (__bf16)v1.w;
            *(bf16x8*)((char*)As[0] + cb * 16) = o1;
        }
    } else {
        gload_lds16(Ab16 + (size_t)rowa * K + kpa, (char*)As[0] + (offa & ~1023));
        if constexpr (BM == 128)
            gload_lds16(Ab16 + (size_t)rowb * K + kpb, (char*)As[0] + (offb & ~1023));
    }
    gload_lds16(Bb + (size_t)rowa * K + kpa, (char*)Bs[0] + (offa & ~1023));
    gload_lds16(Bb + (size_t)rowb * K + kpb, (char*)Bs[0] + (offb & ~1023));
    __syncthreads();

    int buf = 0;
    for (int k0 = 0; k0 < K; k0 += 32) {
        bool pf = (k0 + 32 < K);
        float4 u0{}, v0{}, u1{}, v1{};
        if (pf) {               // issue next-tile loads (A regs if AF32, B gload)
            int kn = k0 + 32;
            if constexpr (AF32) {
                u0 = *(const float4*)(Abf + (size_t)rA0 * K + kn + kA0);
                v0 = *(const float4*)(Abf + (size_t)rA0 * K + kn + kA0 + 4);
                if constexpr (BM == 128) {
                    u1 = *(const float4*)(Abf + (size_t)rA1 * K + kn + kA1);
                    v1 = *(const float4*)(Abf + (size_t)rA1 * K + kn + kA1 + 4);
                }
            } else {
                gload_lds16(Ab16 + (size_t)rowa * K + kn + kpa, (char*)As[buf ^ 1] + (offa & ~1023));
                if constexpr (BM == 128)
                    gload_lds16(Ab16 + (size_t)rowb * K + kn + kpb, (char*)As[buf ^ 1] + (offb & ~1023));
            }
            gload_lds16(Bb + (size_t)rowa * K + kn + kpa, (char*)Bs[buf ^ 1] + (offa & ~1023));
            gload_lds16(Bb + (size_t)rowb * K + kn + kpb, (char*)Bs[buf ^ 1] + (offb & ~1023));
        }
        bf16x8 af[MI], bf[4];
        #pragma unroll
        for (int mi = 0; mi < MI; ++mi)
            af[mi] = *(const bf16x8*)&As[buf][(wr + mi * 16 + lr) * 32 + lg * 8];
        #pragma unroll
        for (int ni = 0; ni < 4; ++ni)
            bf[ni] = *(const bf16x8*)&Bs[buf][(wc + ni * 16 + lr) * 32 + lg * 8];
        #pragma unroll
        for (int mi = 0; mi < MI; ++mi)
            #pragma unroll
            for (int ni = 0; ni < 4; ++ni)
                acc[mi][ni] = MFMA_BF16(af[mi], bf[ni], acc[mi][ni]);
        if (AF32 && pf) {       // cvt + LDS write after compute (loads landed)
            bf16x8 o0;
            o0[0] = (__bf16)u0.x; o0[1] = (__bf16)u0.y; o0[2] = (__bf16)u0.z; o0[3] = (__bf16)u0.w;
            o0[4] = (__bf16)v0.x; o0[5] = (__bf16)v0.y; o0[6] = (__bf16)v0.z; o0[7] = (__bf16)v0.w;
            *(bf16x8*)((char*)As[buf ^ 1] + ca * 16) = o0;
            if constexpr (BM == 128) {
                bf16x8 o1;
                o1[0] = (__bf16)u1.x; o1[1] = (__bf16)u1.y; o1[2] = (__bf16)u1.z; o1[3] = (__bf16)u1.w;
                o1[4] = (__bf16)v1.x; o1[5] = (__bf16)v1.y; o1[6] = (__bf16)v1.z; o1[7] = (__bf16)v1.w;
                *(bf16x8*)((char*)As[buf ^ 1] + cb * 16) = o1;
            }
        }
        __syncthreads();                 // drains gloads (vmcnt) + lds writes (lgkm)
        buf ^= 1;
    }

    #pragma unroll
    for (int mi = 0; mi < MI; ++mi) {
        #pragma unroll
        for (int ni = 0; ni < 4; ++ni) {
            int col = bn * 128 + wc + ni * 16 + lr;
            float bv = bias[col];
            int row0 = bm * BM + wr + mi * 16 + lg * 4;
            if constexpr (MODE == 2) {
                if (col < H_D) {         // K-half -> kb[row][col], stride H_D
                    uint16_t* kb = (uint16_t*)Cv;
                    #pragma unroll
                    for (int j = 0; j < 4; ++j)
                        kb[(size_t)(row0 + j) * H_D + col] = f2bf(acc[mi][ni][j] + bv);
                } else {                 // V-half -> vT[(b*16+hh)*64+dd][sk], packed
                    int dall = col - H_D;
                    int hh = dall >> 6, dd = dall & 63;
                    int bb = row0 >> 11, sk0 = row0 & 2047;  // 128-tiles don't cross b
                    uint16_t p0 = f2bf(acc[mi][ni][0] + bv);
                    uint16_t p1 = f2bf(acc[mi][ni][1] + bv);
                    uint16_t p2 = f2bf(acc[mi][ni][2] + bv);
                    uint16_t p3 = f2bf(acc[mi][ni][3] + bv);
                    uint32_t lo = (uint32_t)p0 | ((uint32_t)p1 << 16);
                    uint32_t hi = (uint32_t)p2 | ((uint32_t)p3 << 16);
                    *(uint2*)&vTb[((size_t)(bb * 16 + hh) * 64 + dd) * H_SK + sk0] =
                        make_uint2(lo, hi);
                }
            } else {
                #pragma unroll
                for (int j = 0; j < 4; ++j) {
                    float v = acc[mi][ni][j] + bv;
                    if constexpr (MODE == 0)
                        ((uint16_t*)Cv)[(size_t)(row0 + j) * N + col] = f2bf(v);
                    else
                        ((float*)Cv)[(size_t)(row0 + j) * N + col] = v;
                }
            }
        }
    }
}

// q-GEMM (blocks 0..511, <0,64,f32A>) + kv-GEMM (blocks 512..1535, <2,128,f32A>).
// q sub-grid = 512 ≡ 0 mod 8, so bid%8 == sub-wg%8 -> XCD swizzle stays valid.
__global__ __launch_bounds__(256) void qkv_gemm_kernel(
    const float* __restrict__ x, const uint16_t* __restrict__ WqT,
    const float* __restrict__ bq, uint16_t* __restrict__ qb,
    const float* __restrict__ ctx, const uint16_t* __restrict__ WkvT,
    const float* __restrict__ bkv, uint16_t* __restrict__ kb,
    uint16_t* __restrict__ vTb)
{
    __shared__ char smem[32768];
    int bid = blockIdx.x;
    if (bid < 512)
        gemm_body<0, 64, true>(x, WqT, bq, qb, nullptr, H_B * H_SQ, H_D, H_D,
                               bid, 512, smem);
    else
        gemm_body<2, 128, true>(ctx, WkvT, bkv, kb, vTb, H_B * H_SK, 2 * H_D, H_D,
                                bid - 512, 1024, smem);
}

__global__ __launch_bounds__(256) void proj_gemm_kernel(
    const uint16_t* __restrict__ ab, const uint16_t* __restrict__ WpT,
    const float* __restrict__ bp, float* __restrict__ out)
{
    __shared__ char smem[24576];
    gemm_body<1, 64, false>(ab, WpT, bp, out, nullptr, H_B * H_SQ, H_D, H_D,
                            blockIdx.x, 512, smem);
}

// ---------------- flash attention (r14 verified; + T5 setprio) ------------------
// grid 1024; panel-swizzled decode pins each (b,h) panel to one XCD's L2.
// K/V double-buffered via global_load_lds (both-sides XOR swizzle), one
// barrier/tile. p_lds [4][16][64] + row-XOR (LDS 40960 = 4 blocks/CU).
// Lane-local defer-max trigger; DPP reduce only on the rare rescale path.
// setprio(1) around MFMA clusters (T5: attn blocks independent -> waves at
// heterogeneous phases -> scheduler can prefer MFMA-entering waves).
__global__ __launch_bounds__(256) void attn_kernel(
    const uint16_t* __restrict__ qb, const uint16_t* __restrict__ kb,
    const uint16_t* __restrict__ vT, const float* __restrict__ mask,
    uint16_t* __restrict__ ab)
{
    __shared__ uint16_t Ks[2][64 * 64];   // [row k][64 d], rows 128B, swizzled cols
    __shared__ uint16_t Vs[2][64 * 64];   // [row d][64 k]
    __shared__ uint16_t p_lds[4][16][64]; // stride 64 + row-XOR -> 8192 B

    int bid = blockIdx.x;
    int xcd = bid & 7;
    int kk = bid >> 3;               // 0..127
    int qt = kk & 15;
    int bh = xcd + 8 * (kk >> 4);    // bijective; panel blocks share bid%8
    int b = bh >> 4, hh = bh & 15;

    int t = threadIdx.x;
    int w = t >> 6, l = t & 63;
    int lr = l & 15, lg = l >> 4;

    // Q fragments straight from global (once per block)
    const uint16_t* qrow = qb + (size_t)(b * H_SQ + qt * 64 + w * 16 + lr) * H_D + hh * H_DH;
    bf16x8 qf0 = *(const bf16x8*)(qrow + lg * 8);
    bf16x8 qf1 = *(const bf16x8*)(qrow + 32 + lg * 8);

    f32x4 acc[4];
    #pragma unroll
    for (int i = 0; i < 4; ++i) acc[i] = {0.f, 0.f, 0.f, 0.f};
    float mrow[4], lsum[4];   // lsum = per-lane PARTIAL (this lane's ni columns)
    #pragma unroll
    for (int j = 0; j < 4; ++j) { mrow[j] = -1e30f; lsum[j] = 0.f; }

    const float SC  = 0.18033688011112042f;   // log2(e)/8
    const float L2E = 1.4426950408889634f;

    // per-lane chunk geometry for staging (16B chunks, 512 per 64x64 tile)
    // chunk c: row r = c>>3, lds col16 cL = c&7, global col16 = cL ^ (r&7)
    int c0 = w * 64 + l;
    int r0 = c0 >> 3,          gc0 = ((c0 & 7) ^ (r0 & 7)) * 8;
    int c1 = 256 + c0;
    int r1 = c1 >> 3,          gc1 = ((c1 & 7) ^ (r1 & 7)) * 8;
    int ldsoff = (w * 64) * 16;               // wave-uniform byte offset, instr 0
    const uint16_t* kbase = kb + (size_t)b * H_SK * H_D + hh * H_DH;
    const uint16_t* vbase = vT + (size_t)bh * H_DH * H_SK;

    // p_lds XOR keys
    int xkbase = (lg & 1) << 5;               // write key base; | (j<<3) per j
    int rdkey  = (lr & 7) << 3;               // read key for row lr

    // prologue: stage tile 0, preload mask(0) premultiplied by log2(e)
    float msk_nxt[4];
    {
        gload_lds16(kbase + (size_t)r0 * H_D + gc0, (char*)Ks[0] + ldsoff);
        gload_lds16(kbase + (size_t)r1 * H_D + gc1, (char*)Ks[0] + ldsoff + 4096);
        gload_lds16(vbase + (size_t)r0 * H_SK + gc0, (char*)Vs[0] + ldsoff);
        gload_lds16(vbase + (size_t)r1 * H_SK + gc1, (char*)Vs[0] + ldsoff + 4096);
        #pragma unroll
        for (int ni = 0; ni < 4; ++ni) msk_nxt[ni] = mask[b * H_SK + ni * 16 + lr] * L2E;
    }
    __syncthreads();   // implicit vmcnt(0): tile 0 landed

    int cur = 0;
    for (int kt = 0; kt < H_SK / 64; ++kt) {
        float msk_cur[4];
        #pragma unroll
        for (int ni = 0; ni < 4; ++ni) msk_cur[ni] = msk_nxt[ni];

        if (kt + 1 < H_SK / 64) {        // stage next tile into other buffer
            int sk1 = (kt + 1) * 64;
            int nxt = cur ^ 1;
            gload_lds16(kbase + (size_t)(sk1 + r0) * H_D + gc0, (char*)Ks[nxt] + ldsoff);
            gload_lds16(kbase + (size_t)(sk1 + r1) * H_D + gc1, (char*)Ks[nxt] + ldsoff + 4096);
            // V^T rows are d (stride H_SK); k-offset sk1 adds AFTER row*stride
            gload_lds16(vbase + (size_t)r0 * H_SK + sk1 + gc0, (char*)Vs[nxt] + ldsoff);
            gload_lds16(vbase + (size_t)r1 * H_SK + sk1 + gc1, (char*)Vs[nxt] + ldsoff + 4096);
            #pragma unroll
            for (int ni = 0; ni < 4; ++ni) msk_nxt[ni] = mask[b * H_SK + sk1 + ni * 16 + lr] * L2E;
        }

        const uint16_t* Kb = Ks[cur];
        const uint16_t* Vb = Vs[cur];
        int sw = (lg ^ (lr & 7)) * 8;    // swizzled col (elements) for frag reads

        // S = Q K^T
        f32x4 s[4];
        #pragma unroll
        for (int ni = 0; ni < 4; ++ni) s[ni] = {0.f, 0.f, 0.f, 0.f};
        __builtin_amdgcn_s_setprio(1);
        #pragma unroll
        for (int ni = 0; ni < 4; ++ni) {
            bf16x8 kf0 = *(const bf16x8*)&Kb[(ni * 16 + lr) * 64 + sw];
            bf16x8 kf1 = *(const bf16x8*)&Kb[(ni * 16 + lr) * 64 + (sw ^ 32)];
            s[ni] = MFMA_BF16(qf0, kf0, s[ni]);
            s[ni] = MFMA_BF16(qf1, kf1, s[ni]);
        }
        __builtin_amdgcn_s_setprio(0);

        // online softmax, exp2 domain — lane-local defer-max test; DPP reduce
        // only inside the (rare) rescale branch
        float lg2[4][4], mxl[4];
        #pragma unroll
        for (int j = 0; j < 4; ++j) {
            float a0 = fmaf(s[0][j], SC, msk_cur[0]);
            float a1 = fmaf(s[1][j], SC, msk_cur[1]);
            float a2 = fmaf(s[2][j], SC, msk_cur[2]);
            float a3 = fmaf(s[3][j], SC, msk_cur[3]);
            lg2[0][j] = a0; lg2[1][j] = a1; lg2[2][j] = a2; lg2[3][j] = a3;
            mxl[j] = fmaxf(fmaxf(a0, a1), fmaxf(a2, a3));
        }
        int grow = 0;
        #pragma unroll
        for (int j = 0; j < 4; ++j)
            grow |= (mxl[j] > mrow[j] + 8.0f) ? 1 : 0;
        if (__any(grow)) {
            #pragma unroll
            for (int j = 0; j < 4; ++j) {
                float mx = dpp_max16(mxl[j]);
                float nm = fmaxf(mrow[j], mx);
                float alpha = EXP2(mrow[j] - nm);
                mrow[j] = nm;
                lsum[j] *= alpha;          // partial: linear in alpha, stays valid
                #pragma unroll
                for (int ni = 0; ni < 4; ++ni) acc[ni][j] *= alpha;
            }
        }
        #pragma unroll
        for (int ni = 0; ni < 4; ++ni)
            #pragma unroll
            for (int j = 0; j < 4; ++j) {
                float p = EXP2(lg2[ni][j] - mrow[j]);
                lsum[j] += p;              // per-lane partial; no cross-lane here
                uint32_t pk;
                asm("v_cvt_pk_bf16_f32 %0, %1, %2" : "=v"(pk) : "v"(p), "v"(p));
                p_lds[w][lg * 4 + j][(ni * 16 + lr) ^ (xkbase | (j << 3))] = (uint16_t)pk;
            }

        // O += P V  (p_lds wave-private; compiler inserts lgkm waits)
        int pc0 = (lg * 8) ^ rdkey;
        bf16x8 pf0 = *(const bf16x8*)&p_lds[w][lr][pc0];
        bf16x8 pf1 = *(const bf16x8*)&p_lds[w][lr][pc0 ^ 32];
        __builtin_amdgcn_s_setprio(1);
        #pragma unroll
        for (int ni = 0; ni < 4; ++ni) {
            bf16x8 vf0 = *(const bf16x8*)&Vb[(ni * 16 + lr) * 64 + sw];
            bf16x8 vf1 = *(const bf16x8*)&Vb[(ni * 16 + lr) * 64 + (sw ^ 32)];
            acc[ni] = MFMA_BF16(pf0, vf0, acc[ni]);
            acc[ni] = MFMA_BF16(pf1, vf1, acc[ni]);
        }
        __builtin_amdgcn_s_setprio(0);

        __syncthreads();   // drains this iter's gloads (vmcnt 0) + protects buffers
        cur ^= 1;
    }

    // single cross-lane sum reduce at the end (16-lane row groups)
    float inv[4];
    #pragma unroll
    for (int j = 0; j < 4; ++j) inv[j] = 1.0f / dpp_sum16(lsum[j]);
    #pragma unroll
    for (int ni = 0; ni < 4; ++ni)
        #pragma unroll
        for (int j = 0; j < 4; ++j) {
            int row = qt * 64 + w * 16 + lg * 4 + j;
            int col = hh * H_DH + ni * 16 + lr;
            ab[(size_t)(b * H_SQ + row) * H_D + col] = f2bf(acc[ni][j] * inv[j]);
        }
}

// ---------------- host ----------------------------------------------------------
extern "C" void kernel_launch(void* const* d_in, const int* in_sizes, int n_in,
                              void* d_out, int out_size, void* d_ws, size_t ws_size,
                              hipStream_t stream) {
    const float* x    = (const float*)d_in[0];
    const float* ctx  = (const float*)d_in[1];
    const float* mask = (const float*)d_in[2];
    const float* Wq   = (const float*)d_in[3];
    const float* bq   = (const float*)d_in[4];
    const float* Wkv  = (const float*)d_in[5];
    const float* bkv  = (const float*)d_in[6];
    const float* Wp   = (const float*)d_in[7];
    const float* bp   = (const float*)d_in[8];
    float* out = (float*)d_out;

    char* ws = (char*)d_ws;
    uint16_t* ab   = (uint16_t*)(ws + 0);          //  8MB (attn out)
    uint16_t* vTb  = (uint16_t*)(ws + 8388608);    // 16MB
    uint16_t* WqT  = (uint16_t*)(ws + 25165824);   //  2MB
    uint16_t* WkvT = (uint16_t*)(ws + 27262976);   //  4MB
    uint16_t* WpT  = (uint16_t*)(ws + 31457280);   //  2MB
    uint16_t* qb   = (uint16_t*)(ws + 33554432);   //  8MB
    uint16_t* kb   = (uint16_t*)(ws + 41943040);   // 16MB -> total 58MB

    prep_kernel<<<4096, 256, 0, stream>>>(Wq, WqT, Wkv, WkvT, Wp, WpT);

    qkv_gemm_kernel<<<1536, 256, 0, stream>>>(x, WqT, bq, qb, ctx, WkvT, bkv, kb, vTb);

    attn_kernel<<<H_B * H_NH * (H_SQ / 64), 256, 0, stream>>>(qb, kb, vTb, mask, ab);

    proj_gemm_kernel<<<512, 256, 0, stream>>>(ab, WpT, bp, out);
}

// Round 16
// 166.481 us; speedup vs baseline: 1.1798x; 1.1798x over previous
//
#include <hip/hip_runtime.h>
#include <stdint.h>

#define H_B  4
#define H_SQ 1024
#define H_SK 2048
#define H_D  1024
#define H_NH 16
#define H_DH 64

typedef __bf16 bf16x8 __attribute__((ext_vector_type(8)));
typedef float  f32x4  __attribute__((ext_vector_type(4)));

__device__ __forceinline__ uint16_t f2bf(float f) {
    union { float f; uint32_t u; } v; v.f = f;
    uint32_t r = v.u + 0x7fffu + ((v.u >> 16) & 1u);
    return (uint16_t)(r >> 16);
}

__device__ __forceinline__ void gload_lds16(const void* g, void* l) {
    __builtin_amdgcn_global_load_lds(
        (const __attribute__((address_space(1))) uint32_t*)g,
        (__attribute__((address_space(3))) uint32_t*)l, 16, 0, 0);
}

#define MFMA_BF16(a, b, c) __builtin_amdgcn_mfma_f32_16x16x32_bf16((a), (b), (c), 0, 0, 0)
#define EXP2(x) __builtin_amdgcn_exp2f(x)

// DPP crosslane (VALU pipe — not DS): xor within 16-lane row groups
template <int CTRL>
__device__ __forceinline__ float dpp_xor(float v) {
    return __builtin_bit_cast(float,
        __builtin_amdgcn_update_dpp(__builtin_bit_cast(int, v),
                                    __builtin_bit_cast(int, v),
                                    CTRL, 0xF, 0xF, false));
}
#define DPP_XOR1 0xB1   // quad_perm(1,0,3,2)
#define DPP_XOR2 0x4E   // quad_perm(2,3,0,1)
#define DPP_XOR4 0x141  // row_half_mirror
#define DPP_XOR8 0x140  // row_mirror

__device__ __forceinline__ float dpp_max16(float v) {
    v = fmaxf(v, dpp_xor<DPP_XOR1>(v));
    v = fmaxf(v, dpp_xor<DPP_XOR2>(v));
    v = fmaxf(v, dpp_xor<DPP_XOR4>(v));
    v = fmaxf(v, dpp_xor<DPP_XOR8>(v));
    return v;
}
__device__ __forceinline__ float dpp_sum16(float v) {
    v += dpp_xor<DPP_XOR1>(v);
    v += dpp_xor<DPP_XOR2>(v);
    v += dpp_xor<DPP_XOR4>(v);
    v += dpp_xor<DPP_XOR8>(v);
    return v;
}

// ---------------- prep: 3 weight transposes + 2 f32->bf16 converts, 1 dispatch --
// blocks 0..4095: wtrans (bx = bid&127 over n: 32 Wq | 64 Wkv | 32 Wp; ky = bid>>7)
// blocks 4096.. : grid-stride cvt over x then ctx (as one index space)
__global__ __launch_bounds__(256) void prep_kernel(
    const float* __restrict__ x, uint16_t* __restrict__ xb,
    const float* __restrict__ ctx, uint16_t* __restrict__ ctxb,
    const float* __restrict__ Wq, uint16_t* __restrict__ WqT,
    const float* __restrict__ Wkv, uint16_t* __restrict__ WkvT,
    const float* __restrict__ Wp, uint16_t* __restrict__ WpT)
{
    __shared__ float tile[32][33];
    int bid = blockIdx.x;
    int t = threadIdx.x;
    if (bid < 4096) {
        int bx = bid & 127, k0 = (bid >> 7) * 32;
        const float* W; uint16_t* WT; int N, n0;
        if (bx < 32)      { W = Wq;  WT = WqT;  N = 1024; n0 = bx * 32; }
        else if (bx < 96) { W = Wkv; WT = WkvT; N = 2048; n0 = (bx - 32) * 32; }
        else              { W = Wp;  WT = WpT;  N = 1024; n0 = (bx - 96) * 32; }
        int tx = t & 31, ty = t >> 5;            // (32,8) reshaped
        #pragma unroll
        for (int i = ty; i < 32; i += 8)
            tile[i][tx] = W[(size_t)(k0 + i) * N + n0 + tx];
        __syncthreads();
        #pragma unroll
        for (int i = ty; i < 32; i += 8)
            WT[(size_t)(n0 + i) * 1024 + k0 + tx] = f2bf(tile[tx][i]);
    } else {
        const int n4a = (H_B * H_SQ * H_D) / 4;
        const int n4b = (H_B * H_SK * H_D) / 4;
        int i = (bid - 4096) * 256 + t;
        int stride = (gridDim.x - 4096) * 256;
        int tot = n4a + n4b;
        for (; i < tot; i += stride) {
            float4 v;
            if (i < n4a) v = ((const float4*)x)[i];
            else         v = ((const float4*)ctx)[i - n4a];
            ushort4 o;
            o.x = f2bf(v.x); o.y = f2bf(v.y); o.z = f2bf(v.z); o.w = f2bf(v.w);
            if (i < n4a) ((ushort4*)xb)[i] = o;
            else         ((ushort4*)ctxb)[i - n4a] = o;
        }
    }
}

// ---------------- GEMM body: C[M][N] = A[M][K] @ BT[N][K]^T + bias, bf16 in -----
// 2-phase double-buffered LDS. BM: 128 (4x4 acc/wave) or 64 (2x4).
// MODE 0: bf16 C. MODE 1: f32 C.
// MODE 2 (kv projection, BM=128): cols < H_D -> kb[row][col] (stride H_D);
//   cols >= H_D -> vT[(b*16+hh)*64+dd][sk] transposed, packed uint2 (fused vtrans).
// wg/nwg passed explicitly so multiple GEMMs can share one dispatch.
template <int MODE, int BM>
__device__ __forceinline__ void gemm_body(
    const uint16_t* __restrict__ A, const uint16_t* __restrict__ BT,
    const float* __restrict__ bias, void* __restrict__ Cv,
    uint16_t* __restrict__ vTb, int M, int N, int K,
    int wg, int nwg, char* smem)
{
    constexpr int MI = BM / 32;              // acc rows of 16x16 frags per wave
    uint16_t (*As)[BM * 32] = (uint16_t (*)[BM * 32])smem;
    uint16_t (*Bs)[128 * 32] = (uint16_t (*)[128 * 32])(smem + 2 * BM * 32 * 2);

    int nbn = N >> 7;
    int cpx = nwg >> 3;                         // nwg divisible by 8 for all our shapes
    wg = (wg & 7) * cpx + (wg >> 3);            // XCD-aware swizzle (bijective)
    int bm = wg / nbn, bn = wg % nbn;

    int t = threadIdx.x;
    int w = t >> 6, l = t & 63;
    int lr = l & 15, lg = l >> 4;
    int wr = (w >> 1) * (BM / 2), wc = (w & 1) * 64;

    const uint16_t* Ab = A + (size_t)bm * BM * K;
    const uint16_t* Bb = BT + (size_t)bn * 128 * K;

    // per-thread staging chunk geometry: chunk c -> row c>>2, 16B piece c&3
    int ca = w * 64 + l;
    int rowa = ca >> 2, kpa = (ca & 3) * 8;
    int cb = 256 + ca;
    int rowb = cb >> 2, kpb = (cb & 3) * 8;
    int offa = ca * 16;          // linear LDS byte offsets (dest = base + lane*16)
    int offb = cb * 16;

    f32x4 acc[MI][4];
    #pragma unroll
    for (int i = 0; i < MI; ++i)
        #pragma unroll
        for (int j = 0; j < 4; ++j) acc[i][j] = {0.f, 0.f, 0.f, 0.f};

    // prologue: stage k0 = 0 into buffer 0 (A: BM*32 tile; 64-row tile = 1 instr)
    gload_lds16(Ab + (size_t)rowa * K + kpa, (char*)As[0] + (offa & ~1023));
    if constexpr (BM == 128)
        gload_lds16(Ab + (size_t)rowb * K + kpb, (char*)As[0] + (offb & ~1023));
    gload_lds16(Bb + (size_t)rowa * K + kpa, (char*)Bs[0] + (offa & ~1023));
    gload_lds16(Bb + (size_t)rowb * K + kpb, (char*)Bs[0] + (offb & ~1023));
    __syncthreads();

    int buf = 0;
    for (int k0 = 0; k0 < K; k0 += 32) {
        if (k0 + 32 < K) {               // stage next K-tile into other buffer
            int kn = k0 + 32;
            gload_lds16(Ab + (size_t)rowa * K + kn + kpa, (char*)As[buf ^ 1] + (offa & ~1023));
            if constexpr (BM == 128)
                gload_lds16(Ab + (size_t)rowb * K + kn + kpb, (char*)As[buf ^ 1] + (offb & ~1023));
            gload_lds16(Bb + (size_t)rowa * K + kn + kpa, (char*)Bs[buf ^ 1] + (offa & ~1023));
            gload_lds16(Bb + (size_t)rowb * K + kn + kpb, (char*)Bs[buf ^ 1] + (offb & ~1023));
        }
        bf16x8 af[MI], bf[4];
        #pragma unroll
        for (int mi = 0; mi < MI; ++mi)
            af[mi] = *(const bf16x8*)&As[buf][(wr + mi * 16 + lr) * 32 + lg * 8];
        #pragma unroll
        for (int ni = 0; ni < 4; ++ni)
            bf[ni] = *(const bf16x8*)&Bs[buf][(wc + ni * 16 + lr) * 32 + lg * 8];
        #pragma unroll
        for (int mi = 0; mi < MI; ++mi)
            #pragma unroll
            for (int ni = 0; ni < 4; ++ni)
                acc[mi][ni] = MFMA_BF16(af[mi], bf[ni], acc[mi][ni]);
        __syncthreads();                 // drains staging vmcnt + read handoff
        buf ^= 1;
    }

    #pragma unroll
    for (int mi = 0; mi < MI; ++mi) {
        #pragma unroll
        for (int ni = 0; ni < 4; ++ni) {
            int col = bn * 128 + wc + ni * 16 + lr;
            float bv = bias[col];
            int row0 = bm * BM + wr + mi * 16 + lg * 4;
            if constexpr (MODE == 2) {
                if (col < H_D) {         // K-half -> kb[row][col], stride H_D
                    uint16_t* kb = (uint16_t*)Cv;
                    #pragma unroll
                    for (int j = 0; j < 4; ++j)
                        kb[(size_t)(row0 + j) * H_D + col] = f2bf(acc[mi][ni][j] + bv);
                } else {                 // V-half -> vT[(b*16+hh)*64+dd][sk], packed
                    int dall = col - H_D;
                    int hh = dall >> 6, dd = dall & 63;
                    int bb = row0 >> 11, sk0 = row0 & 2047;  // 128-tiles don't cross b
                    uint16_t p0 = f2bf(acc[mi][ni][0] + bv);
                    uint16_t p1 = f2bf(acc[mi][ni][1] + bv);
                    uint16_t p2 = f2bf(acc[mi][ni][2] + bv);
                    uint16_t p3 = f2bf(acc[mi][ni][3] + bv);
                    uint32_t lo = (uint32_t)p0 | ((uint32_t)p1 << 16);
                    uint32_t hi = (uint32_t)p2 | ((uint32_t)p3 << 16);
                    *(uint2*)&vTb[((size_t)(bb * 16 + hh) * 64 + dd) * H_SK + sk0] =
                        make_uint2(lo, hi);
                }
            } else {
                #pragma unroll
                for (int j = 0; j < 4; ++j) {
                    float v = acc[mi][ni][j] + bv;
                    if constexpr (MODE == 0)
                        ((uint16_t*)Cv)[(size_t)(row0 + j) * N + col] = f2bf(v);
                    else
                        ((float*)Cv)[(size_t)(row0 + j) * N + col] = v;
                }
            }
        }
    }
}

// q-GEMM (blocks 0..511, <0,64>) + kv-GEMM (blocks 512..1535, <2,128>) fused.
// q sub-grid = 512 ≡ 0 mod 8, so bid%8 == sub-wg%8 -> XCD swizzle stays valid.
__global__ __launch_bounds__(256) void qkv_gemm_kernel(
    const uint16_t* __restrict__ xb, const uint16_t* __restrict__ WqT,
    const float* __restrict__ bq, uint16_t* __restrict__ qb,
    const uint16_t* __restrict__ ctxb, const uint16_t* __restrict__ WkvT,
    const float* __restrict__ bkv, uint16_t* __restrict__ kb,
    uint16_t* __restrict__ vTb)
{
    __shared__ char smem[32768];
    int bid = blockIdx.x;
    if (bid < 512)
        gemm_body<0, 64>(xb, WqT, bq, qb, nullptr, H_B * H_SQ, H_D, H_D,
                         bid, 512, smem);
    else
        gemm_body<2, 128>(ctxb, WkvT, bkv, kb, vTb, H_B * H_SK, 2 * H_D, H_D,
                          bid - 512, 1024, smem);
}

__global__ __launch_bounds__(256) void proj_gemm_kernel(
    const uint16_t* __restrict__ ab, const uint16_t* __restrict__ WpT,
    const float* __restrict__ bp, float* __restrict__ out)
{
    __shared__ char smem[24576];
    gemm_body<1, 64>(ab, WpT, bp, out, nullptr, H_B * H_SQ, H_D, H_D,
                     blockIdx.x, 512, smem);
}

// ---------------- flash attention (r14 verified; + T5 setprio) ------------------
// grid 1024; panel-swizzled decode pins each (b,h) panel to one XCD's L2.
// K/V double-buffered via global_load_lds (both-sides XOR swizzle), one
// barrier/tile. p_lds [4][16][64] + row-XOR (LDS 40960 = 4 blocks/CU).
// Lane-local defer-max trigger; DPP reduce only on the rare rescale path.
// setprio(1) around MFMA clusters (T5).
__global__ __launch_bounds__(256) void attn_kernel(
    const uint16_t* __restrict__ qb, const uint16_t* __restrict__ kb,
    const uint16_t* __restrict__ vT, const float* __restrict__ mask,
    uint16_t* __restrict__ ab)
{
    __shared__ uint16_t Ks[2][64 * 64];   // [row k][64 d], rows 128B, swizzled cols
    __shared__ uint16_t Vs[2][64 * 64];   // [row d][64 k]
    __shared__ uint16_t p_lds[4][16][64]; // stride 64 + row-XOR -> 8192 B

    int bid = blockIdx.x;
    int xcd = bid & 7;
    int kk = bid >> 3;               // 0..127
    int qt = kk & 15;
    int bh = xcd + 8 * (kk >> 4);    // bijective; panel blocks share bid%8
    int b = bh >> 4, hh = bh & 15;

    int t = threadIdx.x;
    int w = t >> 6, l = t & 63;
    int lr = l & 15, lg = l >> 4;

    // Q fragments straight from global (once per block)
    const uint16_t* qrow = qb + (size_t)(b * H_SQ + qt * 64 + w * 16 + lr) * H_D + hh * H_DH;
    bf16x8 qf0 = *(const bf16x8*)(qrow + lg * 8);
    bf16x8 qf1 = *(const bf16x8*)(qrow + 32 + lg * 8);

    f32x4 acc[4];
    #pragma unroll
    for (int i = 0; i < 4; ++i) acc[i] = {0.f, 0.f, 0.f, 0.f};
    float mrow[4], lsum[4];   // lsum = per-lane PARTIAL (this lane's ni columns)
    #pragma unroll
    for (int j = 0; j < 4; ++j) { mrow[j] = -1e30f; lsum[j] = 0.f; }

    const float SC  = 0.18033688011112042f;   // log2(e)/8
    const float L2E = 1.4426950408889634f;

    // per-lane chunk geometry for staging (16B chunks, 512 per 64x64 tile)
    // chunk c: row r = c>>3, lds col16 cL = c&7, global col16 = cL ^ (r&7)
    int c0 = w * 64 + l;
    int r0 = c0 >> 3,          gc0 = ((c0 & 7) ^ (r0 & 7)) * 8;
    int c1 = 256 + c0;
    int r1 = c1 >> 3,          gc1 = ((c1 & 7) ^ (r1 & 7)) * 8;
    int ldsoff = (w * 64) * 16;               // wave-uniform byte offset, instr 0
    const uint16_t* kbase = kb + (size_t)b * H_SK * H_D + hh * H_DH;
    const uint16_t* vbase = vT + (size_t)bh * H_DH * H_SK;

    // p_lds XOR keys
    int xkbase = (lg & 1) << 5;               // write key base; | (j<<3) per j
    int rdkey  = (lr & 7) << 3;               // read key for row lr

    // prologue: stage tile 0, preload mask(0) premultiplied by log2(e)
    float msk_nxt[4];
    {
        gload_lds16(kbase + (size_t)r0 * H_D + gc0, (char*)Ks[0] + ldsoff);
        gload_lds16(kbase + (size_t)r1 * H_D + gc1, (char*)Ks[0] + ldsoff + 4096);
        gload_lds16(vbase + (size_t)r0 * H_SK + gc0, (char*)Vs[0] + ldsoff);
        gload_lds16(vbase + (size_t)r1 * H_SK + gc1, (char*)Vs[0] + ldsoff + 4096);
        #pragma unroll
        for (int ni = 0; ni < 4; ++ni) msk_nxt[ni] = mask[b * H_SK + ni * 16 + lr] * L2E;
    }
    __syncthreads();   // implicit vmcnt(0): tile 0 landed

    int cur = 0;
    for (int kt = 0; kt < H_SK / 64; ++kt) {
        float msk_cur[4];
        #pragma unroll
        for (int ni = 0; ni < 4; ++ni) msk_cur[ni] = msk_nxt[ni];

        if (kt + 1 < H_SK / 64) {        // stage next tile into other buffer
            int sk1 = (kt + 1) * 64;
            int nxt = cur ^ 1;
            gload_lds16(kbase + (size_t)(sk1 + r0) * H_D + gc0, (char*)Ks[nxt] + ldsoff);
            gload_lds16(kbase + (size_t)(sk1 + r1) * H_D + gc1, (char*)Ks[nxt] + ldsoff + 4096);
            // V^T rows are d (stride H_SK); k-offset sk1 adds AFTER row*stride
            gload_lds16(vbase + (size_t)r0 * H_SK + sk1 + gc0, (char*)Vs[nxt] + ldsoff);
            gload_lds16(vbase + (size_t)r1 * H_SK + sk1 + gc1, (char*)Vs[nxt] + ldsoff + 4096);
            #pragma unroll
            for (int ni = 0; ni < 4; ++ni) msk_nxt[ni] = mask[b * H_SK + sk1 + ni * 16 + lr] * L2E;
        }

        const uint16_t* Kb = Ks[cur];
        const uint16_t* Vb = Vs[cur];
        int sw = (lg ^ (lr & 7)) * 8;    // swizzled col (elements) for frag reads

        // S = Q K^T
        f32x4 s[4];
        #pragma unroll
        for (int ni = 0; ni < 4; ++ni) s[ni] = {0.f, 0.f, 0.f, 0.f};
        __builtin_amdgcn_s_setprio(1);
        #pragma unroll
        for (int ni = 0; ni < 4; ++ni) {
            bf16x8 kf0 = *(const bf16x8*)&Kb[(ni * 16 + lr) * 64 + sw];
            bf16x8 kf1 = *(const bf16x8*)&Kb[(ni * 16 + lr) * 64 + (sw ^ 32)];
            s[ni] = MFMA_BF16(qf0, kf0, s[ni]);
            s[ni] = MFMA_BF16(qf1, kf1, s[ni]);
        }
        __builtin_amdgcn_s_setprio(0);

        // online softmax, exp2 domain — lane-local defer-max test; DPP reduce
        // only inside the (rare) rescale branch
        float lg2[4][4], mxl[4];
        #pragma unroll
        for (int j = 0; j < 4; ++j) {
            float a0 = fmaf(s[0][j], SC, msk_cur[0]);
            float a1 = fmaf(s[1][j], SC, msk_cur[1]);
            float a2 = fmaf(s[2][j], SC, msk_cur[2]);
            float a3 = fmaf(s[3][j], SC, msk_cur[3]);
            lg2[0][j] = a0; lg2[1][j] = a1; lg2[2][j] = a2; lg2[3][j] = a3;
            mxl[j] = fmaxf(fmaxf(a0, a1), fmaxf(a2, a3));
        }
        int grow = 0;
        #pragma unroll
        for (int j = 0; j < 4; ++j)
            grow |= (mxl[j] > mrow[j] + 8.0f) ? 1 : 0;
        if (__any(grow)) {
            #pragma unroll
            for (int j = 0; j < 4; ++j) {
                float mx = dpp_max16(mxl[j]);
                float nm = fmaxf(mrow[j], mx);
                float alpha = EXP2(mrow[j] - nm);
                mrow[j] = nm;
                lsum[j] *= alpha;          // partial: linear in alpha, stays valid
                #pragma unroll
                for (int ni = 0; ni < 4; ++ni) acc[ni][j] *= alpha;
            }
        }
        #pragma unroll
        for (int ni = 0; ni < 4; ++ni)
            #pragma unroll
            for (int j = 0; j < 4; ++j) {
                float p = EXP2(lg2[ni][j] - mrow[j]);
                lsum[j] += p;              // per-lane partial; no cross-lane here
                uint32_t pk;
                asm("v_cvt_pk_bf16_f32 %0, %1, %2" : "=v"(pk) : "v"(p), "v"(p));
                p_lds[w][lg * 4 + j][(ni * 16 + lr) ^ (xkbase | (j << 3))] = (uint16_t)pk;
            }

        // O += P V  (p_lds wave-private; compiler inserts lgkm waits)
        int pc0 = (lg * 8) ^ rdkey;
        bf16x8 pf0 = *(const bf16x8*)&p_lds[w][lr][pc0];
        bf16x8 pf1 = *(const bf16x8*)&p_lds[w][lr][pc0 ^ 32];
        __builtin_amdgcn_s_setprio(1);
        #pragma unroll
        for (int ni = 0; ni < 4; ++ni) {
            bf16x8 vf0 = *(const bf16x8*)&Vb[(ni * 16 + lr) * 64 + sw];
            bf16x8 vf1 = *(const bf16x8*)&Vb[(ni * 16 + lr) * 64 + (sw ^ 32)];
            acc[ni] = MFMA_BF16(pf0, vf0, acc[ni]);
            acc[ni] = MFMA_BF16(pf1, vf1, acc[ni]);
        }
        __builtin_amdgcn_s_setprio(0);

        __syncthreads();   // drains this iter's gloads (vmcnt 0) + protects buffers
        cur ^= 1;
    }

    // single cross-lane sum reduce at the end (16-lane row groups)
    float inv[4];
    #pragma unroll
    for (int j = 0; j < 4; ++j) inv[j] = 1.0f / dpp_sum16(lsum[j]);
    #pragma unroll
    for (int ni = 0; ni < 4; ++ni)
        #pragma unroll
        for (int j = 0; j < 4; ++j) {
            int row = qt * 64 + w * 16 + lg * 4 + j;
            int col = hh * H_DH + ni * 16 + lr;
            ab[(size_t)(b * H_SQ + row) * H_D + col] = f2bf(acc[ni][j] * inv[j]);
        }
}

// ---------------- host ----------------------------------------------------------
extern "C" void kernel_launch(void* const* d_in, const int* in_sizes, int n_in,
                              void* d_out, int out_size, void* d_ws, size_t ws_size,
                              hipStream_t stream) {
    const float* x    = (const float*)d_in[0];
    const float* ctx  = (const float*)d_in[1];
    const float* mask = (const float*)d_in[2];
    const float* Wq   = (const float*)d_in[3];
    const float* bq   = (const float*)d_in[4];
    const float* Wkv  = (const float*)d_in[5];
    const float* bkv  = (const float*)d_in[6];
    const float* Wp   = (const float*)d_in[7];
    const float* bp   = (const float*)d_in[8];
    float* out = (float*)d_out;

    char* ws = (char*)d_ws;
    uint16_t* xb   = (uint16_t*)(ws + 0);          //  8MB (reused as ab after q GEMM)
    uint16_t* ctxb = (uint16_t*)(ws + 8388608);    // 16MB
    uint16_t* vTb  = (uint16_t*)(ws + 25165824);   // 16MB (written BY kv GEMM -> no alias with ctxb)
    uint16_t* WqT  = (uint16_t*)(ws + 41943040);   //  2MB
    uint16_t* WkvT = (uint16_t*)(ws + 44040192);   //  4MB
    uint16_t* WpT  = (uint16_t*)(ws + 48234496);   //  2MB
    uint16_t* qb   = (uint16_t*)(ws + 50331648);   //  8MB
    uint16_t* kb   = (uint16_t*)(ws + 58720256);   // 16MB -> total 72MB
    uint16_t* ab   = xb;                            // alias: xb dead after q GEMM

    prep_kernel<<<7168, 256, 0, stream>>>(x, xb, ctx, ctxb, Wq, WqT, Wkv, WkvT, Wp, WpT);

    qkv_gemm_kernel<<<1536, 256, 0, stream>>>(xb, WqT, bq, qb, ctxb, WkvT, bkv, kb, vTb);

    attn_kernel<<<H_B * H_NH * (H_SQ / 64), 256, 0, stream>>>(qb, kb, vTb, mask, ab);

    proj_gemm_kernel<<<512, 256, 0, stream>>>(ab, WpT, bp, out);
}